// Round 1
// baseline (272.801 us; speedup 1.0000x reference)
//
#include <hip/hip_runtime.h>
#include <hip/hip_bf16.h>

typedef __attribute__((ext_vector_type(8))) short short8;
typedef __attribute__((ext_vector_type(4))) float f32x4;

#define BN 4
#define PN 1024
#define NN 16
#define C1N 64
#define C2N 64
#define KN 13
#define AN 12
#define KDIM 9984   // C1N*KN*AN
#define NDIM 768    // C2N*AN
#define MDIM 4096   // BN*PN

__device__ inline unsigned short f2bf(float x){
    unsigned int u = __float_as_uint(x);
    unsigned int r = (u + 0x7fffu + ((u >> 16) & 1u)) >> 16;
    return (unsigned short)r;
}

// ---------------- Kernel 1: inter_w softmax weights ----------------
// one thread per (b,p); writes iw[(b*P+p)*12 + a][16] fp32
__global__ __launch_bounds__(256) void k_interw(const int* __restrict__ nbr,
                                                const float* __restrict__ vert,
                                                const float* __restrict__ vs,
                                                float* __restrict__ iw)
{
    int tid = blockIdx.x * 256 + threadIdx.x;
    if (tid >= MDIM) return;
    int b = tid >> 10;
    float vx = vert[tid*3+0], vy = vert[tid*3+1], vz = vert[tid*3+2];
    float dnx[NN], dny[NN], dnz[NN];
    #pragma unroll
    for (int n = 0; n < NN; n++){
        int idx = nbr[tid*NN + n];
        int g = (b << 10) + idx;
        float dx = vert[g*3+0] - vx;
        float dy = vert[g*3+1] - vy;
        float dz = vert[g*3+2] - vz;
        float nrm = sqrtf(dx*dx + dy*dy + dz*dz);
        float inv = 1.0f / fmaxf(nrm, 1e-12f);
        dnx[n] = dx*inv; dny[n] = dy*inv; dnz[n] = dz*inv;
    }
    for (int a = 0; a < AN; a++){
        float sx = vs[a*3+0], sy = vs[a*3+1], sz = vs[a*3+2];
        float sn = sqrtf(sx*sx + sy*sy + sz*sz);
        float si = 1.0f / fmaxf(sn, 1e-12f);
        sx *= si; sy *= si; sz *= si;
        float t[NN];
        float mx = -1e30f;
        #pragma unroll
        for (int n = 0; n < NN; n++){
            t[n] = dnx[n]*sx + dny[n]*sy + dnz[n]*sz;
            mx = fmaxf(mx, t[n]);
        }
        float s = 0.0f;
        #pragma unroll
        for (int n = 0; n < NN; n++){ t[n] = expf(t[n] - mx); s += t[n]; }
        float inv = 1.0f / s;
        #pragma unroll
        for (int n = 0; n < NN; n++) iw[((size_t)tid*AN + a)*NN + n] = t[n]*inv;
    }
}

// ---------------- Kernel 2: W_eff -> B matrix [n=(d*12+r)][kk=(c*13+k)*12+a] bf16 ----------------
__global__ __launch_bounds__(256) void k_beff(const float* __restrict__ W,
                                              const int* __restrict__ idx_map,
                                              const int* __restrict__ tiv,   // (12,13)
                                              const int* __restrict__ tir,   // (12,12)
                                              unsigned short* __restrict__ Bm)
{
    int t = blockIdx.x * 256 + threadIdx.x;   // < 768*9984 = 7,667,712
    if (t >= NDIM * KDIM) return;
    int nout = t / KDIM;
    int kk   = t - nout * KDIM;
    int c = kk / (KN*AN);
    int rem = kk - c * (KN*AN);
    int k = rem / AN;
    int a = rem - k * AN;
    int d = nout / AN;
    int r = nout - d * AN;
    int s36 = idx_map[ tiv[r*KN + k]*AN + tir[r*AN + a] ];
    float val = W[((d << 6) + c)*36 + s36];
    Bm[t] = f2bf(val);
}

// ---------------- Kernel 3: new_feat -> A matrix [m=(b*P+p)][kk] bf16 ----------------
// one block per (b,p)
__global__ __launch_bounds__(256) void k_newfeat(const int* __restrict__ nbr,
                                                 const float* __restrict__ fm,
                                                 const float* __restrict__ iw,
                                                 unsigned short* __restrict__ Am)
{
    __shared__ float fnb[C1N][NN][AN];   // 49152 B
    __shared__ float iws[AN][NN];
    __shared__ int   nbs[NN];
    int t = threadIdx.x;
    int bid = blockIdx.x;          // b*1024 + p
    int b = bid >> 10, p = bid & 1023;
    size_t fmb = (size_t)b * (C1N * PN * AN);   // b*786432
    size_t abase = (size_t)bid * KDIM;

    if (t < NN) nbs[t] = nbr[bid*NN + t];
    if (t < AN*NN) iws[t >> 4][t & 15] = iw[(size_t)bid * (AN*NN) + t];

    // k = 12 slice: feature_map itself (no LDS dependency)
    for (int i = 0; i < 3; i++){
        int idx = t + i*256;               // < 768
        int c = idx / AN, a = idx - c*AN;
        Am[abase + (c*KN + 12)*AN + a] = f2bf(fm[fmb + c*(PN*AN) + p*AN + a]);
    }
    __syncthreads();

    // gather neighbor features into LDS
    for (int n = 0; n < NN; n++){
        size_t base = fmb + (size_t)nbs[n]*AN;
        for (int i = 0; i < 3; i++){
            int idx = t + i*256;
            int c = idx / AN, a = idx - c*AN;
            fnb[c][n][a] = fm[base + c*(PN*AN) + a];
        }
    }
    __syncthreads();

    // each thread: 3 (c,a) pairs, all 12 k's
    for (int i = 0; i < 3; i++){
        int idx = t + i*256;
        int c = idx / AN, a = idx - c*AN;
        float f[NN];
        #pragma unroll
        for (int n = 0; n < NN; n++) f[n] = fnb[c][n][a];
        #pragma unroll
        for (int k = 0; k < AN; k++){
            float acc = 0.0f;
            #pragma unroll
            for (int n = 0; n < NN; n++) acc += iws[k][n] * f[n];
            Am[abase + (c*KN + k)*AN + a] = f2bf(acc);
        }
    }
}

// ---------------- Kernel 4: GEMM  out[b,d,p,r] = sum_kk Am[m][kk]*Bm[n][kk] ----------------
// 64x64 tile, 4 waves (2x2), 16x16x32 bf16 MFMA, K-step 32
__global__ __launch_bounds__(256) void k_gemm(const unsigned short* __restrict__ Am,
                                              const unsigned short* __restrict__ Bm,
                                              float* __restrict__ out)
{
    __shared__ short A_lds[64][40];   // +8 pad: row stride 80B -> conflict-light
    __shared__ short B_lds[64][40];
    int t = threadIdx.x;
    int m0 = blockIdx.x * 64;
    int n0 = blockIdx.y * 64;
    int lane = t & 63, w = t >> 6;
    int wr = w >> 1, wc = w & 1;
    int l15 = lane & 15;
    int kofs = (lane >> 4) * 8;

    int row = t >> 2, ch = t & 3;     // staging: 64 rows x 4 16B-chunks
    const unsigned short* ga = Am + (size_t)(m0 + row) * KDIM + ch*8;
    const unsigned short* gb = Bm + (size_t)(n0 + row) * KDIM + ch*8;

    f32x4 acc[2][2] = {};

    for (int kk0 = 0; kk0 < KDIM; kk0 += 32){
        int4 va = *reinterpret_cast<const int4*>(ga + kk0);
        int4 vb = *reinterpret_cast<const int4*>(gb + kk0);
        *reinterpret_cast<int4*>(&A_lds[row][ch*8]) = va;
        *reinterpret_cast<int4*>(&B_lds[row][ch*8]) = vb;
        __syncthreads();
        short8 a0 = *reinterpret_cast<const short8*>(&A_lds[wr*32 +      l15][kofs]);
        short8 a1 = *reinterpret_cast<const short8*>(&A_lds[wr*32 + 16 + l15][kofs]);
        short8 b0 = *reinterpret_cast<const short8*>(&B_lds[wc*32 +      l15][kofs]);
        short8 b1 = *reinterpret_cast<const short8*>(&B_lds[wc*32 + 16 + l15][kofs]);
        acc[0][0] = __builtin_amdgcn_mfma_f32_16x16x32_bf16(a0, b0, acc[0][0], 0, 0, 0);
        acc[0][1] = __builtin_amdgcn_mfma_f32_16x16x32_bf16(a0, b1, acc[0][1], 0, 0, 0);
        acc[1][0] = __builtin_amdgcn_mfma_f32_16x16x32_bf16(a1, b0, acc[1][0], 0, 0, 0);
        acc[1][1] = __builtin_amdgcn_mfma_f32_16x16x32_bf16(a1, b1, acc[1][1], 0, 0, 0);
        __syncthreads();
    }

    // epilogue: C/D layout col = lane&15, row = (lane>>4)*4 + q   [m89-verified]
    #pragma unroll
    for (int i = 0; i < 2; i++){
        #pragma unroll
        for (int j = 0; j < 2; j++){
            int col = n0 + wc*32 + j*16 + l15;      // n = d*12 + r
            int d = col / AN, r = col - d*AN;
            #pragma unroll
            for (int q = 0; q < 4; q++){
                int mrow = m0 + wr*32 + i*16 + (lane >> 4)*4 + q;   // m = b*1024 + p
                int b = mrow >> 10, p = mrow & 1023;
                out[((size_t)((b << 6) + d) * PN + p) * AN + r] = acc[i][j][q];
            }
        }
    }
}

extern "C" void kernel_launch(void* const* d_in, const int* in_sizes, int n_in,
                              void* d_out, int out_size, void* d_ws, size_t ws_size,
                              hipStream_t stream)
{
    const int*   nbr     = (const int*)  d_in[0];
    const float* vert    = (const float*)d_in[1];
    const float* fm      = (const float*)d_in[2];
    const float* W       = (const float*)d_in[3];
    const float* vs      = (const float*)d_in[4];
    const int*   idx_map = (const int*)  d_in[5];
    const int*   tiv     = (const int*)  d_in[6];
    const int*   tir     = (const int*)  d_in[7];
    float* out = (float*)d_out;

    char* ws = (char*)d_ws;
    float*          iw = (float*)ws;                                  // 3,145,728 B
    unsigned short* Bm = (unsigned short*)(ws + 3145728);             // 15,335,424 B
    unsigned short* Am = (unsigned short*)(ws + 3145728 + 15335424);  // 81,788,928 B

    k_interw <<<MDIM/256, 256, 0, stream>>>(nbr, vert, vs, iw);
    k_beff   <<<(NDIM*KDIM)/256, 256, 0, stream>>>(W, idx_map, tiv, tir, Bm);
    k_newfeat<<<MDIM, 256, 0, stream>>>(nbr, fm, iw, Am);
    dim3 g(MDIM/64, NDIM/64);
    k_gemm   <<<g, 256, 0, stream>>>(Am, Bm, out);
}

// Round 2
// 255.348 us; speedup vs baseline: 1.0683x; 1.0683x over previous
//
#include <hip/hip_runtime.h>
#include <hip/hip_bf16.h>

typedef __attribute__((ext_vector_type(8))) short short8;
typedef __attribute__((ext_vector_type(4))) short s16x4;
typedef __attribute__((ext_vector_type(4))) float f32x4;

#define BN 4
#define PN 1024
#define NN 16
#define C1N 64
#define C2N 64
#define KN 13
#define AN 12
#define KDIM 9984   // C1N*KN*AN
#define NDIM 768    // C2N*AN
#define MDIM 4096   // BN*PN
#define BK 32

__device__ inline unsigned short f2bf(float x){
    unsigned int u = __float_as_uint(x);
    unsigned int r = (u + 0x7fffu + ((u >> 16) & 1u)) >> 16;
    return (unsigned short)r;
}

// async global->LDS, 16B per lane. LDS dest = wave-uniform base + lane*16.
__device__ __forceinline__ void gload16(const unsigned short* g, unsigned short* l){
    __builtin_amdgcn_global_load_lds(
        (const __attribute__((address_space(1))) unsigned int*)(unsigned long long)(uintptr_t)g,
        (__attribute__((address_space(3))) unsigned int*)(unsigned int)(uintptr_t)l,
        16, 0, 0);
}

// ---------------- Kernel 1: inter_w softmax weights ----------------
// thread per (point, a); iw[(b*P+p)*12 + a][16] fp32
__global__ __launch_bounds__(256) void k_interw(const int* __restrict__ nbr,
                                                const float* __restrict__ vert,
                                                const float* __restrict__ vs,
                                                float* __restrict__ iw)
{
    int t = blockIdx.x * 256 + threadIdx.x;      // < 49152
    if (t >= MDIM * AN) return;
    int pt = t / AN, a = t - pt * AN;
    int b = pt >> 10;
    float sx = vs[a*3+0], sy = vs[a*3+1], sz = vs[a*3+2];
    float sn = sqrtf(sx*sx + sy*sy + sz*sz);
    float si = 1.0f / fmaxf(sn, 1e-12f);
    sx *= si; sy *= si; sz *= si;
    float vx = vert[pt*3+0], vy = vert[pt*3+1], vz = vert[pt*3+2];
    float tt[NN];
    float mx = -1e30f;
    #pragma unroll
    for (int n = 0; n < NN; n++){
        int g = (b << 10) + nbr[pt*NN + n];
        float dx = vert[g*3+0] - vx;
        float dy = vert[g*3+1] - vy;
        float dz = vert[g*3+2] - vz;
        float nr = sqrtf(dx*dx + dy*dy + dz*dz);
        float inv = 1.0f / fmaxf(nr, 1e-12f);
        tt[n] = (dx*sx + dy*sy + dz*sz) * inv;
        mx = fmaxf(mx, tt[n]);
    }
    float s = 0.0f;
    #pragma unroll
    for (int n = 0; n < NN; n++){ tt[n] = expf(tt[n] - mx); s += tt[n]; }
    float inv = 1.0f / s;
    float* dst = iw + (size_t)t * NN;
    #pragma unroll
    for (int q = 0; q < 4; q++){
        float4 v = make_float4(tt[q*4]*inv, tt[q*4+1]*inv, tt[q*4+2]*inv, tt[q*4+3]*inv);
        *(float4*)(dst + q*4) = v;
    }
}

// ---------------- Kernel 2: W_eff -> B matrix [n=(d*12+r)][kk=(c*13+k)*12+a] bf16 ----------------
// thread per (d,r,c,k): 12 contiguous a-values, 24B store
__global__ __launch_bounds__(256) void k_beff(const float* __restrict__ W,
                                              const int* __restrict__ idx_map,
                                              const int* __restrict__ tiv,   // (12,13)
                                              const int* __restrict__ tir,   // (12,12)
                                              unsigned short* __restrict__ Bm)
{
    int t = blockIdx.x * 256 + threadIdx.x;   // < 64*12*64*13 = 638976
    int k = t % KN;
    int rem = t / KN;
    int c = rem & 63; rem >>= 6;
    int r = rem % AN;
    int d = rem / AN;
    int tv = tiv[r*KN + k];
    const float* wrow = W + (size_t)((d << 6) + c) * 36;
    s16x4 v0, v1, v2;
    #pragma unroll
    for (int a = 0; a < AN; a++){
        int s = idx_map[tv*AN + tir[r*AN + a]];
        unsigned short h = f2bf(wrow[s]);
        if (a < 4) v0[a] = (short)h;
        else if (a < 8) v1[a-4] = (short)h;
        else v2[a-8] = (short)h;
    }
    unsigned short* dst = Bm + ((size_t)(d*AN + r) * KDIM + (c*KN + k) * AN);
    s16x4* d4 = (s16x4*)dst;
    d4[0] = v0; d4[1] = v1; d4[2] = v2;
}

// ---------------- Kernel 3: new_feat -> A matrix [m=(b*P+p)][kk] bf16 ----------------
// one block per (b,p); builds the full 9984-row in LDS, writes coalesced int4
__global__ __launch_bounds__(256) void k_newfeat(const int* __restrict__ nbr,
                                                 const float* __restrict__ fm,
                                                 const float* __restrict__ iw,
                                                 unsigned short* __restrict__ Am)
{
    __shared__ float fnb[NN][772];            // [n][c*12+a], pad to 772 for alignment
    __shared__ float selfv[C1N*AN];           // own features
    __shared__ float iws[AN][NN];
    __shared__ int   nbs[NN];
    __shared__ unsigned short anf[KDIM];      // staged bf16 output row (19968 B)
    int t = threadIdx.x;
    int bid = blockIdx.x;
    int b = bid >> 10, p = bid & 1023;
    const float* fmb = fm + (size_t)b * (C1N * PN * AN);

    if (t < NN) nbs[t] = nbr[bid*NN + t];
    if (t < AN*NN) iws[t >> 4][t & 15] = iw[(size_t)bid * (AN*NN) + t];
    __syncthreads();

    // gather neighbor features: 1024 (c,n) pairs, 3 float4 each
    #pragma unroll
    for (int i = 0; i < 4; i++){
        int pr = t*4 + i;                 // c = pr>>4, n = pr&15
        int c = pr >> 4, n = pr & 15;
        const float* src = fmb + ((size_t)c * PN + nbs[n]) * AN;
        float4 v0 = *(const float4*)(src);
        float4 v1 = *(const float4*)(src + 4);
        float4 v2 = *(const float4*)(src + 8);
        *(float4*)&fnb[n][c*AN]     = v0;
        *(float4*)&fnb[n][c*AN + 4] = v1;
        *(float4*)&fnb[n][c*AN + 8] = v2;
    }
    // own features: 192 float4s
    if (t < 192){
        int c = t / 3, q = t - c*3;
        float4 v = *(const float4*)(fmb + ((size_t)c * PN + p) * AN + q*4);
        *(float4*)&selfv[c*AN + q*4] = v;
    }
    __syncthreads();

    // compute: thread owns (c,a) pairs t, t+256, t+512
    #pragma unroll
    for (int i = 0; i < 3; i++){
        int idx = t + i*256;
        int c = idx / AN, a = idx - c*AN;
        float f[NN];
        #pragma unroll
        for (int n = 0; n < NN; n++) f[n] = fnb[n][c*AN + a];
        #pragma unroll
        for (int k = 0; k < AN; k++){
            float acc = 0.0f;
            #pragma unroll
            for (int n = 0; n < NN; n++) acc += iws[k][n] * f[n];
            anf[(c*KN + k)*AN + a] = f2bf(acc);
        }
        anf[(c*KN + 12)*AN + a] = f2bf(selfv[c*AN + a]);
    }
    __syncthreads();

    // coalesced row write: 19968 B = 1248 int4
    const int4* s4 = (const int4*)anf;
    int4* dAm = (int4*)(Am + (size_t)bid * KDIM);
    for (int i = t; i < KDIM/8; i += 256) dAm[i] = s4[i];
}

// ---------------- Kernel 4: GEMM (m97 structure) ----------------
// 128x128 tile, 4 waves (2x2, 64x64 each), 16x16x32 bf16, BK=32, global_load_lds(16), split-K
__global__ __launch_bounds__(256) void k_gemm(const unsigned short* __restrict__ Am,
                                              const unsigned short* __restrict__ Bm,
                                              float* __restrict__ part,
                                              float* __restrict__ out,
                                              int klen, int nsplit)
{
    __shared__ unsigned short Al[128*BK];   // linear (global_load_lds requires it)
    __shared__ unsigned short Bl[128*BK];
    int t = threadIdx.x;
    int lane = t & 63, w = t >> 6;
    int wr = w >> 1, wc = w & 1;
    int l15 = lane & 15;
    int kofs = (lane >> 4) * 8;
    int m0 = blockIdx.x * 128, n0 = blockIdx.y * 128;
    int kbase = blockIdx.z * klen;

    // staging map: chunk c of wave w covers LDS elems [w*1024 + c*512, +512)
    int srow = w*32 + (lane >> 2);
    int scol = (lane & 3) * 8;
    const unsigned short* gA0 = Am + (size_t)(m0 + srow)      * KDIM + scol + kbase;
    const unsigned short* gA1 = Am + (size_t)(m0 + srow + 16) * KDIM + scol + kbase;
    const unsigned short* gB0 = Bm + (size_t)(n0 + srow)      * KDIM + scol + kbase;
    const unsigned short* gB1 = Bm + (size_t)(n0 + srow + 16) * KDIM + scol + kbase;
    unsigned short* lA0 = &Al[w*1024];
    unsigned short* lA1 = &Al[w*1024 + 512];
    unsigned short* lB0 = &Bl[w*1024];
    unsigned short* lB1 = &Bl[w*1024 + 512];

    f32x4 acc[4][4] = {};

    for (int kk = 0; kk < klen; kk += BK){
        gload16(gA0 + kk, lA0);
        gload16(gA1 + kk, lA1);
        gload16(gB0 + kk, lB0);
        gload16(gB1 + kk, lB1);
        __syncthreads();                      // drains vmcnt -> tile ready
        short8 af[4], bf[4];
        #pragma unroll
        for (int i = 0; i < 4; i++)
            af[i] = *(const short8*)&Al[(wr*64 + i*16 + l15)*BK + kofs];
        #pragma unroll
        for (int j = 0; j < 4; j++)
            bf[j] = *(const short8*)&Bl[(wc*64 + j*16 + l15)*BK + kofs];
        #pragma unroll
        for (int i = 0; i < 4; i++){
            #pragma unroll
            for (int j = 0; j < 4; j++)
                acc[i][j] = __builtin_amdgcn_mfma_f32_16x16x32_bf16(af[i], bf[j], acc[i][j], 0, 0, 0);
        }
        __syncthreads();                      // protect LDS before next stage
    }

    // epilogue: C/D layout col=lane&15, row=(lane>>4)*4+q  [m89-verified]
    if (nsplit > 1){
        float* pp = part + (size_t)blockIdx.z * ((size_t)MDIM * NDIM);
        #pragma unroll
        for (int i = 0; i < 4; i++){
            #pragma unroll
            for (int j = 0; j < 4; j++){
                int col = n0 + wc*64 + j*16 + l15;
                #pragma unroll
                for (int q = 0; q < 4; q++){
                    int row = m0 + wr*64 + i*16 + (lane >> 4)*4 + q;
                    pp[(size_t)row * NDIM + col] = acc[i][j][q];
                }
            }
        }
    } else {
        #pragma unroll
        for (int i = 0; i < 4; i++){
            #pragma unroll
            for (int j = 0; j < 4; j++){
                int col = n0 + wc*64 + j*16 + l15;
                int d = col / AN, r = col - d*AN;
                #pragma unroll
                for (int q = 0; q < 4; q++){
                    int row = m0 + wr*64 + i*16 + (lane >> 4)*4 + q;
                    int b = row >> 10, pp2 = row & 1023;
                    out[((size_t)((b << 6) + d) * PN + pp2) * AN + r] = acc[i][j][q];
                }
            }
        }
    }
}

// ---------------- Kernel 5: split-K reduce + scatter to bdpr ----------------
__global__ __launch_bounds__(256) void k_reduce(const float* __restrict__ part,
                                                float* __restrict__ out, int nsplit)
{
    int t = blockIdx.x * 256 + threadIdx.x;        // per float4: MDIM*NDIM/4
    if (t >= MDIM * (NDIM/4)) return;
    int m = t / (NDIM/4);
    int n4 = (t - m * (NDIM/4)) * 4;
    f32x4 s = {};
    for (int z = 0; z < nsplit; z++){
        f32x4 v = *(const f32x4*)(part + (size_t)z * ((size_t)MDIM * NDIM) + (size_t)m * NDIM + n4);
        s += v;
    }
    int b = m >> 10, p = m & 1023;
    int d = n4 / AN, r = n4 - d*AN;    // r in {0,4,8}: never crosses d within 4
    *(f32x4*)(out + ((size_t)((b << 6) + d) * PN + p) * AN + r) = s;
}

extern "C" void kernel_launch(void* const* d_in, const int* in_sizes, int n_in,
                              void* d_out, int out_size, void* d_ws, size_t ws_size,
                              hipStream_t stream)
{
    const int*   nbr     = (const int*)  d_in[0];
    const float* vert    = (const float*)d_in[1];
    const float* fm      = (const float*)d_in[2];
    const float* W       = (const float*)d_in[3];
    const float* vs      = (const float*)d_in[4];
    const int*   idx_map = (const int*)  d_in[5];
    const int*   tiv     = (const int*)  d_in[6];
    const int*   tir     = (const int*)  d_in[7];
    float* out = (float*)d_out;

    char* ws = (char*)d_ws;
    float*          iw   = (float*)ws;                                  // 3,145,728 B
    unsigned short* Bm   = (unsigned short*)(ws + 3145728);             // 15,335,424 B
    unsigned short* Am   = (unsigned short*)(ws + 18481152);            // 81,788,928 B
    float*          part = (float*)(ws + 100270080);

    // split-K factor: as many fp32 partial copies as the workspace allows (max 4)
    long long avail = (long long)ws_size - 100270080LL;
    int nsplit = (int)(avail / 12582912LL);
    if (nsplit > 4) nsplit = 4;
    if (nsplit < 1) nsplit = 1;
    if (nsplit == 3) nsplit = 3;              // 1,2,3,4 all divide 312 K-steps
    int klen = KDIM / nsplit;

    k_interw <<<(MDIM*AN)/256, 256, 0, stream>>>(nbr, vert, vs, iw);
    k_beff   <<<(C2N*AN*C1N*KN)/256, 256, 0, stream>>>(W, idx_map, tiv, tir, Bm);
    k_newfeat<<<MDIM, 256, 0, stream>>>(nbr, fm, iw, Am);
    dim3 g(MDIM/128, NDIM/128, nsplit);
    k_gemm   <<<g, 256, 0, stream>>>(Am, Bm, part, out, klen, nsplit);
    if (nsplit > 1)
        k_reduce<<<(MDIM*(NDIM/4))/256, 256, 0, stream>>>(part, out, nsplit);
}

// Round 3
// 180.682 us; speedup vs baseline: 1.5098x; 1.4132x over previous
//
#include <hip/hip_runtime.h>
#include <hip/hip_bf16.h>

typedef __attribute__((ext_vector_type(8))) short short8;
typedef __attribute__((ext_vector_type(4))) short s16x4;
typedef __attribute__((ext_vector_type(4))) float f32x4;

#define BN 4
#define PN 1024
#define NN 16
#define C1N 64
#define C2N 64
#define KN 13
#define AN 12
#define KDIM 9984   // C1N*KN*AN, kk = k*768 + c*12 + a
#define NDIM 768    // C2N*AN
#define MDIM 4096   // BN*PN
#define BK 32

__device__ inline unsigned short f2bf(float x){
    unsigned int u = __float_as_uint(x);
    unsigned int r = (u + 0x7fffu + ((u >> 16) & 1u)) >> 16;
    return (unsigned short)r;
}

// async global->LDS, 16B per lane. LDS dest = wave-uniform base + lane*16.
__device__ __forceinline__ void gload16(const unsigned short* g, unsigned short* l){
    __builtin_amdgcn_global_load_lds(
        (const __attribute__((address_space(1))) unsigned int*)(unsigned long long)(uintptr_t)g,
        (__attribute__((address_space(3))) unsigned int*)(unsigned int)(uintptr_t)l,
        16, 0, 0);
}

// ---------------- Kernel 1: inter_w softmax weights ----------------
// thread per (point, a); iw[(b*P+p)*12 + a][16] fp32
__global__ __launch_bounds__(256) void k_interw(const int* __restrict__ nbr,
                                                const float* __restrict__ vert,
                                                const float* __restrict__ vs,
                                                float* __restrict__ iw)
{
    int t = blockIdx.x * 256 + threadIdx.x;      // < 49152
    if (t >= MDIM * AN) return;
    int pt = t / AN, a = t - pt * AN;
    int b = pt >> 10;
    float sx = vs[a*3+0], sy = vs[a*3+1], sz = vs[a*3+2];
    float sn = sqrtf(sx*sx + sy*sy + sz*sz);
    float si = 1.0f / fmaxf(sn, 1e-12f);
    sx *= si; sy *= si; sz *= si;
    float vx = vert[pt*3+0], vy = vert[pt*3+1], vz = vert[pt*3+2];
    float tt[NN];
    float mx = -1e30f;
    #pragma unroll
    for (int n = 0; n < NN; n++){
        int g = (b << 10) + nbr[pt*NN + n];
        float dx = vert[g*3+0] - vx;
        float dy = vert[g*3+1] - vy;
        float dz = vert[g*3+2] - vz;
        float nr = sqrtf(dx*dx + dy*dy + dz*dz);
        float inv = 1.0f / fmaxf(nr, 1e-12f);
        tt[n] = (dx*sx + dy*sy + dz*sz) * inv;
        mx = fmaxf(mx, tt[n]);
    }
    float s = 0.0f;
    #pragma unroll
    for (int n = 0; n < NN; n++){ tt[n] = expf(tt[n] - mx); s += tt[n]; }
    float inv = 1.0f / s;
    float* dst = iw + (size_t)t * NN;
    #pragma unroll
    for (int q = 0; q < 4; q++){
        float4 v = make_float4(tt[q*4]*inv, tt[q*4+1]*inv, tt[q*4+2]*inv, tt[q*4+3]*inv);
        *(float4*)(dst + q*4) = v;
    }
}

// ---------------- Kernel 2: W_eff -> B matrix [n=(d*12+r)][kk=k*768+c*12+a] bf16 ----------------
// wave-uniform (d,r,k), lane = c: stores stride 24B -> coalesced
__global__ __launch_bounds__(256) void k_beff(const float* __restrict__ W,
                                              const int* __restrict__ idx_map,
                                              const int* __restrict__ tiv,   // (12,13)
                                              const int* __restrict__ tir,   // (12,12)
                                              unsigned short* __restrict__ Bm)
{
    int t = blockIdx.x * 256 + threadIdx.x;   // < 64*12*13*64 = 638976
    int c = t & 63;
    int rest = t >> 6;          // < 9984
    int k = rest % KN;
    int rest2 = rest / KN;      // < 768
    int r = rest2 % AN;
    int d = rest2 / AN;
    int tv = tiv[r*KN + k];
    const float* wrow = W + (size_t)((d << 6) + c) * 36;
    s16x4 v0, v1, v2;
    #pragma unroll
    for (int a = 0; a < AN; a++){
        int s = idx_map[tv*AN + tir[r*AN + a]];
        unsigned short h = f2bf(wrow[s]);
        if (a < 4) v0[a] = (short)h;
        else if (a < 8) v1[a-4] = (short)h;
        else v2[a-8] = (short)h;
    }
    unsigned short* dst = Bm + ((size_t)(d*AN + r) * KDIM + k*768 + c*AN);
    s16x4* d4 = (s16x4*)dst;
    d4[0] = v0; d4[1] = v1; d4[2] = v2;
}

// ---------------- Kernel 3: new_feat -> A matrix [m][kk=k*768+c*12+a] bf16 ----------------
// wave per point, lane = channel c. 144 fp32 accumulators per lane.
__global__ __launch_bounds__(256) void k_newfeat(const int* __restrict__ nbr,
                                                 const float* __restrict__ fm,
                                                 const float* __restrict__ iw,
                                                 unsigned short* __restrict__ Am)
{
    __shared__ int   nbs_s[4][NN];
    __shared__ float iwT_s[4][NN][AN];      // [wave][n][k]
    int t = threadIdx.x;
    int w = t >> 6, lane = t & 63;
    int m = blockIdx.x * 4 + w;             // point id < 4096
    int b = m >> 10, p = m & 1023;
    const float* fmb = fm + (size_t)b * (C1N * PN * AN);

    if (lane < NN) nbs_s[w][lane] = nbr[m*NN + lane];
    #pragma unroll
    for (int i = 0; i < 3; i++){
        int idx = lane + i*64;              // < 192
        int a = idx >> 4, n = idx & 15;     // iw layout [a][n]
        iwT_s[w][n][a] = iw[(size_t)m * (AN*NN) + idx];
    }
    __syncthreads();

    f32x4 acc[12][3];
    #pragma unroll
    for (int k = 0; k < 12; k++){
        #pragma unroll
        for (int q = 0; q < 3; q++) acc[k][q] = (f32x4){0.f,0.f,0.f,0.f};
    }

    const float* crow = fmb + (size_t)lane * (PN * AN);   // fm[b][c=lane][...]

    #pragma unroll 2
    for (int n = 0; n < NN; n++){
        int pp = nbs_s[w][n];
        const float* src = crow + pp * AN;
        f32x4 v0 = *(const f32x4*)(src);
        f32x4 v1 = *(const f32x4*)(src + 4);
        f32x4 v2 = *(const f32x4*)(src + 8);
        f32x4 w0 = *(const f32x4*)&iwT_s[w][n][0];
        f32x4 w1 = *(const f32x4*)&iwT_s[w][n][4];
        f32x4 w2 = *(const f32x4*)&iwT_s[w][n][8];
        float wk[12] = {w0[0],w0[1],w0[2],w0[3],
                        w1[0],w1[1],w1[2],w1[3],
                        w2[0],w2[1],w2[2],w2[3]};
        #pragma unroll
        for (int k = 0; k < 12; k++){
            acc[k][0] += v0 * wk[k];
            acc[k][1] += v1 * wk[k];
            acc[k][2] += v2 * wk[k];
        }
    }

    // own features (k = 12 slice)
    const float* own = crow + (size_t)p * AN;
    f32x4 s0 = *(const f32x4*)(own);
    f32x4 s1 = *(const f32x4*)(own + 4);
    f32x4 s2 = *(const f32x4*)(own + 8);

    unsigned short* dst = Am + (size_t)m * KDIM + lane * AN;
    #pragma unroll
    for (int k = 0; k < 12; k++){
        s16x4 h0, h1, h2;
        #pragma unroll
        for (int j = 0; j < 4; j++){
            h0[j] = (short)f2bf(acc[k][0][j]);
            h1[j] = (short)f2bf(acc[k][1][j]);
            h2[j] = (short)f2bf(acc[k][2][j]);
        }
        s16x4* o = (s16x4*)(dst + k*768);
        o[0] = h0; o[1] = h1; o[2] = h2;
    }
    {
        s16x4 h0, h1, h2;
        #pragma unroll
        for (int j = 0; j < 4; j++){
            h0[j] = (short)f2bf(s0[j]);
            h1[j] = (short)f2bf(s1[j]);
            h2[j] = (short)f2bf(s2[j]);
        }
        s16x4* o = (s16x4*)(dst + 12*768);
        o[0] = h0; o[1] = h1; o[2] = h2;
    }
}

// ---------------- Kernel 4: GEMM (m97 structure) ----------------
// 128x128 tile, 4 waves (2x2, 64x64 each), 16x16x32 bf16, BK=32, global_load_lds(16), split-K
__global__ __launch_bounds__(256) void k_gemm(const unsigned short* __restrict__ Am,
                                              const unsigned short* __restrict__ Bm,
                                              float* __restrict__ part,
                                              float* __restrict__ out,
                                              int klen, int nsplit)
{
    __shared__ unsigned short Al[128*BK];   // linear (global_load_lds requires it)
    __shared__ unsigned short Bl[128*BK];
    int t = threadIdx.x;
    int lane = t & 63, w = t >> 6;
    int wr = w >> 1, wc = w & 1;
    int l15 = lane & 15;
    int kofs = (lane >> 4) * 8;
    int m0 = blockIdx.x * 128, n0 = blockIdx.y * 128;
    int kbase = blockIdx.z * klen;

    int srow = w*32 + (lane >> 2);
    int scol = (lane & 3) * 8;
    const unsigned short* gA0 = Am + (size_t)(m0 + srow)      * KDIM + scol + kbase;
    const unsigned short* gA1 = Am + (size_t)(m0 + srow + 16) * KDIM + scol + kbase;
    const unsigned short* gB0 = Bm + (size_t)(n0 + srow)      * KDIM + scol + kbase;
    const unsigned short* gB1 = Bm + (size_t)(n0 + srow + 16) * KDIM + scol + kbase;
    unsigned short* lA0 = &Al[w*1024];
    unsigned short* lA1 = &Al[w*1024 + 512];
    unsigned short* lB0 = &Bl[w*1024];
    unsigned short* lB1 = &Bl[w*1024 + 512];

    f32x4 acc[4][4] = {};

    for (int kk = 0; kk < klen; kk += BK){
        gload16(gA0 + kk, lA0);
        gload16(gA1 + kk, lA1);
        gload16(gB0 + kk, lB0);
        gload16(gB1 + kk, lB1);
        __syncthreads();
        short8 af[4], bf[4];
        #pragma unroll
        for (int i = 0; i < 4; i++)
            af[i] = *(const short8*)&Al[(wr*64 + i*16 + l15)*BK + kofs];
        #pragma unroll
        for (int j = 0; j < 4; j++)
            bf[j] = *(const short8*)&Bl[(wc*64 + j*16 + l15)*BK + kofs];
        #pragma unroll
        for (int i = 0; i < 4; i++){
            #pragma unroll
            for (int j = 0; j < 4; j++)
                acc[i][j] = __builtin_amdgcn_mfma_f32_16x16x32_bf16(af[i], bf[j], acc[i][j], 0, 0, 0);
        }
        __syncthreads();
    }

    if (nsplit > 1){
        float* pp = part + (size_t)blockIdx.z * ((size_t)MDIM * NDIM);
        #pragma unroll
        for (int i = 0; i < 4; i++){
            #pragma unroll
            for (int j = 0; j < 4; j++){
                int col = n0 + wc*64 + j*16 + l15;
                #pragma unroll
                for (int q = 0; q < 4; q++){
                    int row = m0 + wr*64 + i*16 + (lane >> 4)*4 + q;
                    pp[(size_t)row * NDIM + col] = acc[i][j][q];
                }
            }
        }
    } else {
        #pragma unroll
        for (int i = 0; i < 4; i++){
            #pragma unroll
            for (int j = 0; j < 4; j++){
                int col = n0 + wc*64 + j*16 + l15;
                int d = col / AN, r = col - d*AN;
                #pragma unroll
                for (int q = 0; q < 4; q++){
                    int row = m0 + wr*64 + i*16 + (lane >> 4)*4 + q;
                    int b = row >> 10, pp2 = row & 1023;
                    out[((size_t)((b << 6) + d) * PN + pp2) * AN + r] = acc[i][j][q];
                }
            }
        }
    }
}

// ---------------- Kernel 5: split-K reduce + scatter to bdpr ----------------
__global__ __launch_bounds__(256) void k_reduce(const float* __restrict__ part,
                                                float* __restrict__ out, int nsplit)
{
    int t = blockIdx.x * 256 + threadIdx.x;        // per float4: MDIM*NDIM/4
    if (t >= MDIM * (NDIM/4)) return;
    int m = t / (NDIM/4);
    int n4 = (t - m * (NDIM/4)) * 4;
    f32x4 s = {};
    for (int z = 0; z < nsplit; z++){
        f32x4 v = *(const f32x4*)(part + (size_t)z * ((size_t)MDIM * NDIM) + (size_t)m * NDIM + n4);
        s += v;
    }
    int b = m >> 10, p = m & 1023;
    int d = n4 / AN, r = n4 - d*AN;    // r in {0,4,8}: never crosses d within 4
    *(f32x4*)(out + ((size_t)((b << 6) + d) * PN + p) * AN + r) = s;
}

extern "C" void kernel_launch(void* const* d_in, const int* in_sizes, int n_in,
                              void* d_out, int out_size, void* d_ws, size_t ws_size,
                              hipStream_t stream)
{
    const int*   nbr     = (const int*)  d_in[0];
    const float* vert    = (const float*)d_in[1];
    const float* fm      = (const float*)d_in[2];
    const float* W       = (const float*)d_in[3];
    const float* vs      = (const float*)d_in[4];
    const int*   idx_map = (const int*)  d_in[5];
    const int*   tiv     = (const int*)  d_in[6];
    const int*   tir     = (const int*)  d_in[7];
    float* out = (float*)d_out;

    char* ws = (char*)d_ws;
    float*          iw   = (float*)ws;                                  // 3,145,728 B
    unsigned short* Bm   = (unsigned short*)(ws + 3145728);             // 15,335,424 B
    unsigned short* Am   = (unsigned short*)(ws + 18481152);            // 81,788,928 B
    float*          part = (float*)(ws + 100270080);

    long long avail = (long long)ws_size - 100270080LL;
    int nsplit = (int)(avail / 12582912LL);
    if (nsplit > 4) nsplit = 4;
    if (nsplit < 1) nsplit = 1;
    int klen = KDIM / nsplit;

    k_interw <<<(MDIM*AN)/256, 256, 0, stream>>>(nbr, vert, vs, iw);
    k_beff   <<<(C2N*AN*C1N*KN)/256, 256, 0, stream>>>(W, idx_map, tiv, tir, Bm);
    k_newfeat<<<MDIM/4, 256, 0, stream>>>(nbr, fm, iw, Am);
    dim3 g(MDIM/128, NDIM/128, nsplit);
    k_gemm   <<<g, 256, 0, stream>>>(Am, Bm, part, out, klen, nsplit);
    if (nsplit > 1)
        k_reduce<<<(MDIM*(NDIM/4))/256, 256, 0, stream>>>(part, out, nsplit);
}